// Round 2
// baseline (2977.669 us; speedup 1.0000x reference)
//
#include <hip/hip_runtime.h>

// GCNConv + ReLU, MI355X. All float tensors fp32 (harness contract), edge_index int32.
// out[d] = relu(dis[d] * (hp[d] + sum_{e:dst=d} hp[src_e]) + b),
//   hp = (x@W) * dis[row],  dis = rsqrt(indeg_dst + 1)   (deg >= 1 due to self-loops)

__global__ void k_zero(unsigned int* __restrict__ cnt, int N) {
  int i = blockIdx.x * blockDim.x + threadIdx.x;
  if (i < N) cnt[i] = 0u;
}

__global__ void k_count(const int* __restrict__ dst, unsigned int* __restrict__ cnt, int E) {
  int e = blockIdx.x * blockDim.x + threadIdx.x;
  if (e < E) atomicAdd(&cnt[dst[e]], 1u);
}

__global__ void k_dis(const unsigned int* __restrict__ cnt, float* __restrict__ dis, int N) {
  int i = blockIdx.x * blockDim.x + threadIdx.x;
  if (i < N) dis[i] = rsqrtf((float)(cnt[i] + 1u));
}

// hp = (x @ W) * dis[row]; hp -> h (fp32, gather source) and -> agg (self-loop init).
// Block: 256 thr, tile 32 rows x 128 cols, K-chunks of 32. Cin=256, Cout=128 hardcoded.
__global__ __launch_bounds__(256) void k_gemm(
    const float* __restrict__ x, const float* __restrict__ W,
    const float* __restrict__ dis,
    float* __restrict__ h, float* __restrict__ agg, int N)
{
  __shared__ float xst[32][36];    // [k][row], stride 36 floats = 144B (16B-aligned rows)
  __shared__ float wsm[32][132];   // [k][col], stride 132 floats = 528B (16B-aligned rows)
  const int tid = threadIdx.x;
  const int row0 = blockIdx.x * 32;
  const int cg = tid & 31;          // cols cg*4 .. cg*4+3
  const int rg = tid >> 5;          // rows rg*4 .. rg*4+3
  float acc[4][4] = {};

  for (int k0 = 0; k0 < 256; k0 += 32) {
    // x tile 32 rows x 32 k: each thread one float4, store transposed (k-major).
    {
      int r = tid >> 3;
      int c = (tid & 7) * 4;
      int row = row0 + r; if (row >= N) row = N - 1;
      const float4 v = *(const float4*)(x + (size_t)row * 256 + k0 + c);
      xst[c + 0][r] = v.x;
      xst[c + 1][r] = v.y;
      xst[c + 2][r] = v.z;
      xst[c + 3][r] = v.w;
    }
    // W tile 32 k x 128 cols: 4 float4 per thread.
    #pragma unroll
    for (int i = 0; i < 4; i++) {
      int idx = tid + i * 256;
      int wr = idx >> 5;
      int wc = (idx & 31) * 4;
      *(float4*)&wsm[wr][wc] = *(const float4*)(W + (size_t)(k0 + wr) * 128 + wc);
    }
    __syncthreads();
    #pragma unroll
    for (int kk = 0; kk < 32; kk++) {
      const float4 wv = *(const float4*)&wsm[kk][cg * 4];
      const float4 xv = *(const float4*)&xst[kk][rg * 4];
      const float xa[4] = {xv.x, xv.y, xv.z, xv.w};
      #pragma unroll
      for (int j = 0; j < 4; j++) {
        acc[j][0] = fmaf(xa[j], wv.x, acc[j][0]);
        acc[j][1] = fmaf(xa[j], wv.y, acc[j][1]);
        acc[j][2] = fmaf(xa[j], wv.z, acc[j][2]);
        acc[j][3] = fmaf(xa[j], wv.w, acc[j][3]);
      }
    }
    __syncthreads();
  }

  #pragma unroll
  for (int j = 0; j < 4; j++) {
    const int row = row0 + rg * 4 + j;
    if (row < N) {
      const float s = dis[row];
      float4 v;
      v.x = acc[j][0] * s; v.y = acc[j][1] * s; v.z = acc[j][2] * s; v.w = acc[j][3] * s;
      *(float4*)(agg + (size_t)row * 128 + cg * 4) = v;
      *(float4*)(h   + (size_t)row * 128 + cg * 4) = v;
    }
  }
}

// 32 lanes per edge: gather float4 of hp[src], atomic-add fp32 into agg[dst].
__global__ __launch_bounds__(256) void k_edge(
    const float* __restrict__ h, const int* __restrict__ src,
    const int* __restrict__ dst, float* __restrict__ agg, int E)
{
  long long t = (long long)blockIdx.x * blockDim.x + threadIdx.x;
  int e = (int)(t >> 5);
  if (e >= E) return;
  int lane = (int)(t & 31);
  int s = src[e];
  int d = dst[e];
  const float4 v = *(const float4*)(h + ((size_t)s << 7) + (lane << 2));
  float* o = agg + ((size_t)d << 7) + (lane << 2);
  unsafeAtomicAdd(o + 0, v.x);
  unsafeAtomicAdd(o + 1, v.y);
  unsafeAtomicAdd(o + 2, v.z);
  unsafeAtomicAdd(o + 3, v.w);
}

// out = relu(dis[row]*agg + b), fp32, float4 per thread.
__global__ void k_final(const float* __restrict__ agg, const float* __restrict__ dis,
                        const float* __restrict__ b, float* __restrict__ out, int N)
{
  int t = blockIdx.x * blockDim.x + threadIdx.x;
  if (t >= N * 32) return;
  int row = t >> 5;
  int c0 = (t & 31) * 4;
  float s = dis[row];
  const float4 a = *(const float4*)(agg + (size_t)row * 128 + c0);
  const float4 bb = *(const float4*)(b + c0);
  float4 o;
  o.x = fmaxf(fmaf(s, a.x, bb.x), 0.f);
  o.y = fmaxf(fmaf(s, a.y, bb.y), 0.f);
  o.z = fmaxf(fmaf(s, a.z, bb.z), 0.f);
  o.w = fmaxf(fmaf(s, a.w, bb.w), 0.f);
  *(float4*)(out + (size_t)row * 128 + c0) = o;
}

extern "C" void kernel_launch(void* const* d_in, const int* in_sizes, int n_in,
                              void* d_out, int out_size, void* d_ws, size_t ws_size,
                              hipStream_t stream)
{
  const float* x  = (const float*)d_in[0];
  const int* ei   = (const int*)d_in[1];
  const float* W  = (const float*)d_in[2];
  const float* b  = (const float*)d_in[3];
  float* out = (float*)d_out;

  const int Cout = in_sizes[3];            // 128
  const int Cin  = in_sizes[2] / Cout;     // 256
  const int N    = in_sizes[0] / Cin;      // 100000
  const int E    = in_sizes[1] / 2;        // 1600000

  const int* src = ei;
  const int* dst = ei + E;

  char* p = (char*)d_ws;
  size_t off = 0;
  unsigned int* cnt = (unsigned int*)(p + off);
  off += (size_t)N * 4;            off = (off + 255) & ~(size_t)255;
  float* dis = (float*)(p + off);
  off += (size_t)N * 4;            off = (off + 255) & ~(size_t)255;
  float* h = (float*)(p + off);
  off += (size_t)N * Cout * 4;     off = (off + 255) & ~(size_t)255;
  float* agg = (float*)(p + off);
  off += (size_t)N * Cout * 4;     // total ~103 MB

  k_zero <<<(N + 255) / 256, 256, 0, stream>>>(cnt, N);
  k_count<<<(E + 255) / 256, 256, 0, stream>>>(dst, cnt, E);
  k_dis  <<<(N + 255) / 256, 256, 0, stream>>>(cnt, dis, N);
  k_gemm <<<(N + 31) / 32, 256, 0, stream>>>(x, W, dis, h, agg, N);
  long long tE = (long long)E * 32;
  k_edge <<<(int)((tE + 255) / 256), 256, 0, stream>>>(h, src, dst, agg, E);
  k_final<<<(N * 32 + 255) / 256, 256, 0, stream>>>(agg, dis, b, out, N);
}

// Round 3
// 530.891 us; speedup vs baseline: 5.6088x; 5.6088x over previous
//
#include <hip/hip_runtime.h>

// GCNConv + ReLU, MI355X. fp32 tensors, edge_index int32.
// out[d] = relu(dis[d] * (hp[d] + sum_{e:dst=d} hp[src_e]) + b),
//   hp = (x@W) * dis[row],  dis = rsqrt(indeg_dst + 1).
// R2: replaced 204.8M fp32 atomics (WRITE_SIZE 3.2GB, 2685us) with device-built
// CSR + register aggregation + fused epilogue.

__global__ void k_zero(unsigned int* __restrict__ cnt, int N) {
  int i = blockIdx.x * blockDim.x + threadIdx.x;
  if (i < N) cnt[i] = 0u;
}

__global__ void k_count(const int* __restrict__ dst, unsigned int* __restrict__ cnt, int E) {
  int e = blockIdx.x * blockDim.x + threadIdx.x;
  if (e < E) atomicAdd(&cnt[dst[e]], 1u);
}

// --- exclusive scan of cnt[0..N) -> rowptr/cursor; dis = rsqrt(cnt+1) ---
__global__ void k_scan1(const unsigned int* __restrict__ cnt, unsigned int* __restrict__ partial, int N) {
  __shared__ unsigned int s[256];
  int t = threadIdx.x;
  int i = blockIdx.x * 256 + t;
  s[t] = (i < N) ? cnt[i] : 0u;
  __syncthreads();
  for (int off = 128; off > 0; off >>= 1) {
    if (t < off) s[t] += s[t + off];
    __syncthreads();
  }
  if (t == 0) partial[blockIdx.x] = s[0];
}

__global__ __launch_bounds__(1024) void k_scan2(unsigned int* __restrict__ partial, int nb) {
  __shared__ unsigned int s[1024];
  int t = threadIdx.x;
  unsigned int v = (t < nb) ? partial[t] : 0u;
  s[t] = v;
  __syncthreads();
  for (int off = 1; off < 1024; off <<= 1) {
    unsigned int u = (t >= off) ? s[t - off] : 0u;
    __syncthreads();
    s[t] += u;
    __syncthreads();
  }
  if (t < nb) partial[t] = s[t] - v;  // exclusive
}

__global__ void k_scan3(const unsigned int* __restrict__ cnt, const unsigned int* __restrict__ partial,
                        int* __restrict__ rowptr, int* __restrict__ cursor,
                        float* __restrict__ dis, int N) {
  __shared__ unsigned int s[256];
  int t = threadIdx.x;
  int i = blockIdx.x * 256 + t;
  unsigned int v = (i < N) ? cnt[i] : 0u;
  s[t] = v;
  __syncthreads();
  for (int off = 1; off < 256; off <<= 1) {
    unsigned int u = (t >= off) ? s[t - off] : 0u;
    __syncthreads();
    s[t] += u;
    __syncthreads();
  }
  if (i < N) {
    unsigned int excl = s[t] - v + partial[blockIdx.x];
    rowptr[i] = (int)excl;
    cursor[i] = (int)excl;
    dis[i] = rsqrtf((float)(v + 1u));
    if (i == N - 1) rowptr[N] = (int)(excl + v);
  }
}

__global__ void k_scatter(const int* __restrict__ src, const int* __restrict__ dst,
                          int* __restrict__ cursor, int* __restrict__ srcs, int E) {
  int e = blockIdx.x * blockDim.x + threadIdx.x;
  if (e < E) {
    int d = dst[e];
    int pos = atomicAdd(&cursor[d], 1);
    srcs[pos] = src[e];
  }
}

// hp = (x @ W) * dis[row] -> h. 256 thr, tile 32 rows x 128 cols, K-chunk 32.
__global__ __launch_bounds__(256) void k_gemm(
    const float* __restrict__ x, const float* __restrict__ W,
    const float* __restrict__ dis, float* __restrict__ h, int N)
{
  __shared__ float xst[32][36];
  __shared__ float wsm[32][132];
  const int tid = threadIdx.x;
  const int row0 = blockIdx.x * 32;
  const int cg = tid & 31;
  const int rg = tid >> 5;
  float acc[4][4] = {};

  for (int k0 = 0; k0 < 256; k0 += 32) {
    {
      int r = tid >> 3;
      int c = (tid & 7) * 4;
      int row = row0 + r; if (row >= N) row = N - 1;
      const float4 v = *(const float4*)(x + (size_t)row * 256 + k0 + c);
      xst[c + 0][r] = v.x;
      xst[c + 1][r] = v.y;
      xst[c + 2][r] = v.z;
      xst[c + 3][r] = v.w;
    }
    #pragma unroll
    for (int i = 0; i < 4; i++) {
      int idx = tid + i * 256;
      int wr = idx >> 5;
      int wc = (idx & 31) * 4;
      *(float4*)&wsm[wr][wc] = *(const float4*)(W + (size_t)(k0 + wr) * 128 + wc);
    }
    __syncthreads();
    #pragma unroll
    for (int kk = 0; kk < 32; kk++) {
      const float4 wv = *(const float4*)&wsm[kk][cg * 4];
      const float4 xv = *(const float4*)&xst[kk][rg * 4];
      const float xa[4] = {xv.x, xv.y, xv.z, xv.w};
      #pragma unroll
      for (int j = 0; j < 4; j++) {
        acc[j][0] = fmaf(xa[j], wv.x, acc[j][0]);
        acc[j][1] = fmaf(xa[j], wv.y, acc[j][1]);
        acc[j][2] = fmaf(xa[j], wv.z, acc[j][2]);
        acc[j][3] = fmaf(xa[j], wv.w, acc[j][3]);
      }
    }
    __syncthreads();
  }

  #pragma unroll
  for (int j = 0; j < 4; j++) {
    const int row = row0 + rg * 4 + j;
    if (row < N) {
      const float s = dis[row];
      float4 v;
      v.x = acc[j][0] * s; v.y = acc[j][1] * s; v.z = acc[j][2] * s; v.w = acc[j][3] * s;
      *(float4*)(h + (size_t)row * 128 + cg * 4) = v;
    }
  }
}

// One half-wave (32 lanes) per dst node; lane owns float4 of 128 channels.
// acc = h[n] (self loop) + sum h[srcs[...]]; out = relu(dis[n]*acc + b).
__global__ __launch_bounds__(256) void k_aggr(
    const float* __restrict__ h, const int* __restrict__ srcs,
    const int* __restrict__ rowptr, const float* __restrict__ dis,
    const float* __restrict__ b, float* __restrict__ out, int N)
{
  const int n = blockIdx.x * 8 + (threadIdx.x >> 5);
  const int lane = threadIdx.x & 31;
  if (n >= N) return;
  const int start = rowptr[n];
  const int end   = rowptr[n + 1];
  const size_t coff = (size_t)(lane << 2);

  const float4 self = *(const float4*)(h + ((size_t)n << 7) + coff);
  float ax = self.x, ay = self.y, az = self.z, aw = self.w;

  for (int base = start; base < end; base += 32) {
    const int k = min(32, end - base);
    const int sidx = (lane < k) ? srcs[base + lane] : 0;
    int j = 0;
    for (; j + 4 <= k; j += 4) {
      const int s0 = __shfl(sidx, j + 0, 32);
      const int s1 = __shfl(sidx, j + 1, 32);
      const int s2 = __shfl(sidx, j + 2, 32);
      const int s3 = __shfl(sidx, j + 3, 32);
      const float4 v0 = *(const float4*)(h + ((size_t)s0 << 7) + coff);
      const float4 v1 = *(const float4*)(h + ((size_t)s1 << 7) + coff);
      const float4 v2 = *(const float4*)(h + ((size_t)s2 << 7) + coff);
      const float4 v3 = *(const float4*)(h + ((size_t)s3 << 7) + coff);
      ax += (v0.x + v1.x) + (v2.x + v3.x);
      ay += (v0.y + v1.y) + (v2.y + v3.y);
      az += (v0.z + v1.z) + (v2.z + v3.z);
      aw += (v0.w + v1.w) + (v2.w + v3.w);
    }
    for (; j < k; j++) {
      const int s0 = __shfl(sidx, j, 32);
      const float4 v0 = *(const float4*)(h + ((size_t)s0 << 7) + coff);
      ax += v0.x; ay += v0.y; az += v0.z; aw += v0.w;
    }
  }

  const float s = dis[n];
  const float4 bb = *(const float4*)(b + (lane << 2));
  float4 o;
  o.x = fmaxf(fmaf(s, ax, bb.x), 0.f);
  o.y = fmaxf(fmaf(s, ay, bb.y), 0.f);
  o.z = fmaxf(fmaf(s, az, bb.z), 0.f);
  o.w = fmaxf(fmaf(s, aw, bb.w), 0.f);
  *(float4*)(out + ((size_t)n << 7) + coff) = o;
}

extern "C" void kernel_launch(void* const* d_in, const int* in_sizes, int n_in,
                              void* d_out, int out_size, void* d_ws, size_t ws_size,
                              hipStream_t stream)
{
  const float* x  = (const float*)d_in[0];
  const int* ei   = (const int*)d_in[1];
  const float* W  = (const float*)d_in[2];
  const float* b  = (const float*)d_in[3];
  float* out = (float*)d_out;

  const int Cout = in_sizes[3];            // 128
  const int Cin  = in_sizes[2] / Cout;     // 256
  const int N    = in_sizes[0] / Cin;      // 100000
  const int E    = in_sizes[1] / 2;        // 1600000

  const int* src = ei;
  const int* dst = ei + E;

  char* p = (char*)d_ws;
  size_t off = 0;
  auto alloc = [&](size_t bytes) { char* q = p + off; off = (off + bytes + 255) & ~(size_t)255; return q; };
  unsigned int* cnt     = (unsigned int*)alloc((size_t)N * 4);
  unsigned int* partial = (unsigned int*)alloc(1024 * 4);
  float* dis            = (float*)alloc((size_t)N * 4);
  int* rowptr           = (int*)alloc(((size_t)N + 1) * 4);
  int* cursor           = (int*)alloc((size_t)N * 4);
  int* srcs             = (int*)alloc((size_t)E * 4);
  float* h              = (float*)alloc((size_t)N * Cout * 4);   // total ~60 MB

  const int nb = (N + 255) / 256;          // 391 <= 1024

  k_zero   <<<nb, 256, 0, stream>>>(cnt, N);
  k_count  <<<(E + 255) / 256, 256, 0, stream>>>(dst, cnt, E);
  k_scan1  <<<nb, 256, 0, stream>>>(cnt, partial, N);
  k_scan2  <<<1, 1024, 0, stream>>>(partial, nb);
  k_scan3  <<<nb, 256, 0, stream>>>(cnt, partial, rowptr, cursor, dis, N);
  k_scatter<<<(E + 255) / 256, 256, 0, stream>>>(src, dst, cursor, srcs, E);
  k_gemm   <<<(N + 31) / 32, 256, 0, stream>>>(x, W, dis, h, N);
  k_aggr   <<<(N + 7) / 8, 256, 0, stream>>>(h, srcs, rowptr, dis, b, out, N);
}

// Round 4
// 398.172 us; speedup vs baseline: 7.4783x; 1.3333x over previous
//
#include <hip/hip_runtime.h>

// GCNConv + ReLU, MI355X. fp32 tensors, edge_index int32.
// out[d] = relu(dis[d] * (hp[d] + sum_{e:dst=d} hp[src_e]) + b),
//   hp = (x@W) * dis[row],  dis = rsqrt(indeg_dst + 1).
// R3: CSR + register aggregation (no float atomics) -> 531us.
// R4: (a) fuse scatter (latency-bound, VALU 0.3%) with GEMM (VALU-bound) in one
//     kernel, interleaved 1:2, to overlap pipes; (b) h in bf16 to halve the
//     aggregation gather traffic (FETCH 399MB -> ~200MB).

__device__ __forceinline__ unsigned short f2bf(float f) {
  unsigned int u = __float_as_uint(f);
  u += 0x7FFFu + ((u >> 16) & 1u);   // RNE
  return (unsigned short)(u >> 16);
}

__global__ void k_zero(unsigned int* __restrict__ cnt, int N) {
  int i = blockIdx.x * blockDim.x + threadIdx.x;
  if (i < N) cnt[i] = 0u;
}

__global__ void k_count(const int* __restrict__ dst, unsigned int* __restrict__ cnt, int E) {
  int e = blockIdx.x * blockDim.x + threadIdx.x;
  if (e < E) atomicAdd(&cnt[dst[e]], 1u);
}

// --- exclusive scan of cnt[0..N) -> rowptr/cursor; dis = rsqrt(cnt+1) ---
__global__ void k_scan1(const unsigned int* __restrict__ cnt, unsigned int* __restrict__ partial, int N) {
  __shared__ unsigned int s[256];
  int t = threadIdx.x;
  int i = blockIdx.x * 256 + t;
  s[t] = (i < N) ? cnt[i] : 0u;
  __syncthreads();
  for (int off = 128; off > 0; off >>= 1) {
    if (t < off) s[t] += s[t + off];
    __syncthreads();
  }
  if (t == 0) partial[blockIdx.x] = s[0];
}

__global__ __launch_bounds__(1024) void k_scan2(unsigned int* __restrict__ partial, int nb) {
  __shared__ unsigned int s[1024];
  int t = threadIdx.x;
  unsigned int v = (t < nb) ? partial[t] : 0u;
  s[t] = v;
  __syncthreads();
  for (int off = 1; off < 1024; off <<= 1) {
    unsigned int u = (t >= off) ? s[t - off] : 0u;
    __syncthreads();
    s[t] += u;
    __syncthreads();
  }
  if (t < nb) partial[t] = s[t] - v;  // exclusive
}

__global__ void k_scan3(const unsigned int* __restrict__ cnt, const unsigned int* __restrict__ partial,
                        int* __restrict__ rowptr, int* __restrict__ cursor,
                        float* __restrict__ dis, int N) {
  __shared__ unsigned int s[256];
  int t = threadIdx.x;
  int i = blockIdx.x * 256 + t;
  unsigned int v = (i < N) ? cnt[i] : 0u;
  s[t] = v;
  __syncthreads();
  for (int off = 1; off < 256; off <<= 1) {
    unsigned int u = (t >= off) ? s[t - off] : 0u;
    __syncthreads();
    s[t] += u;
    __syncthreads();
  }
  if (i < N) {
    unsigned int excl = s[t] - v + partial[blockIdx.x];
    rowptr[i] = (int)excl;
    cursor[i] = (int)excl;
    dis[i] = rsqrtf((float)(v + 1u));
    if (i == N - 1) rowptr[N] = (int)(excl + v);
  }
}

// Fused: gemm tiles (hp=(x@W)*dis -> bf16 h) and CSR scatter, interleaved 1:2.
// GEMM path: 256 thr, tile 32 rows x 128 cols, K-chunk 32, fp32 FMA.
__global__ __launch_bounds__(256) void k_gemm_scatter(
    const float* __restrict__ x, const float* __restrict__ W,
    const float* __restrict__ dis, unsigned short* __restrict__ h, int N,
    const int* __restrict__ src, const int* __restrict__ dst,
    int* __restrict__ cursor, int* __restrict__ srcs, int E,
    int gemmB, int scatB)
{
  __shared__ float xst[32][36];
  __shared__ float wsm[32][132];

  const int id = blockIdx.x;
  bool isGemm;
  int idx;
  if (scatB == 2 * gemmB) {            // exact 1:2 interleave (our shape)
    if (id % 3 == 0) { isGemm = true;  idx = id / 3; }
    else             { isGemm = false; idx = id - 1 - id / 3; }
  } else {                              // generic fallback: segmented
    isGemm = id < gemmB;
    idx = isGemm ? id : id - gemmB;
  }

  const int tid = threadIdx.x;

  if (!isGemm) {
    if (idx < scatB) {
      int e = idx * 256 + tid;
      if (e < E) {
        int d = dst[e];
        int pos = atomicAdd(&cursor[d], 1);
        srcs[pos] = src[e];
      }
    }
    return;
  }
  if (idx >= gemmB) return;

  const int row0 = idx * 32;
  const int cg = tid & 31;
  const int rg = tid >> 5;
  float acc[4][4] = {};

  for (int k0 = 0; k0 < 256; k0 += 32) {
    {
      int r = tid >> 3;
      int c = (tid & 7) * 4;
      int row = row0 + r; if (row >= N) row = N - 1;
      const float4 v = *(const float4*)(x + (size_t)row * 256 + k0 + c);
      xst[c + 0][r] = v.x;
      xst[c + 1][r] = v.y;
      xst[c + 2][r] = v.z;
      xst[c + 3][r] = v.w;
    }
    #pragma unroll
    for (int i = 0; i < 4; i++) {
      int widx = tid + i * 256;
      int wr = widx >> 5;
      int wc = (widx & 31) * 4;
      *(float4*)&wsm[wr][wc] = *(const float4*)(W + (size_t)(k0 + wr) * 128 + wc);
    }
    __syncthreads();
    #pragma unroll
    for (int kk = 0; kk < 32; kk++) {
      const float4 wv = *(const float4*)&wsm[kk][cg * 4];
      const float4 xv = *(const float4*)&xst[kk][rg * 4];
      const float xa[4] = {xv.x, xv.y, xv.z, xv.w};
      #pragma unroll
      for (int j = 0; j < 4; j++) {
        acc[j][0] = fmaf(xa[j], wv.x, acc[j][0]);
        acc[j][1] = fmaf(xa[j], wv.y, acc[j][1]);
        acc[j][2] = fmaf(xa[j], wv.z, acc[j][2]);
        acc[j][3] = fmaf(xa[j], wv.w, acc[j][3]);
      }
    }
    __syncthreads();
  }

  #pragma unroll
  for (int j = 0; j < 4; j++) {
    const int row = row0 + rg * 4 + j;
    if (row < N) {
      const float s = dis[row];
      unsigned int lo = (unsigned int)f2bf(acc[j][0] * s) | ((unsigned int)f2bf(acc[j][1] * s) << 16);
      unsigned int hi = (unsigned int)f2bf(acc[j][2] * s) | ((unsigned int)f2bf(acc[j][3] * s) << 16);
      *(uint2*)(h + (size_t)row * 128 + cg * 4) = make_uint2(lo, hi);
    }
  }
}

// One half-wave (32 lanes) per dst node; lane owns 4 of 128 channels (bf16 h).
// acc = h[n] (self loop) + sum h[srcs[...]]; out = relu(dis[n]*acc + b).
__global__ __launch_bounds__(256) void k_aggr(
    const unsigned short* __restrict__ h, const int* __restrict__ srcs,
    const int* __restrict__ rowptr, const float* __restrict__ dis,
    const float* __restrict__ b, float* __restrict__ out, int N)
{
  const int n = blockIdx.x * 8 + (threadIdx.x >> 5);
  const int lane = threadIdx.x & 31;
  if (n >= N) return;
  const int start = rowptr[n];
  const int end   = rowptr[n + 1];
  const size_t coff = (size_t)(lane << 2);   // channel offset (elements)

  float ax, ay, az, aw;
  {
    const uint2 v = *(const uint2*)(h + ((size_t)n << 7) + coff);
    ax = __uint_as_float(v.x << 16);
    ay = __uint_as_float(v.x & 0xFFFF0000u);
    az = __uint_as_float(v.y << 16);
    aw = __uint_as_float(v.y & 0xFFFF0000u);
  }

  for (int base = start; base < end; base += 32) {
    const int k = min(32, end - base);
    const int sidx = (lane < k) ? srcs[base + lane] : 0;
    int j = 0;
    for (; j + 4 <= k; j += 4) {
      const int s0 = __shfl(sidx, j + 0, 32);
      const int s1 = __shfl(sidx, j + 1, 32);
      const int s2 = __shfl(sidx, j + 2, 32);
      const int s3 = __shfl(sidx, j + 3, 32);
      const uint2 v0 = *(const uint2*)(h + ((size_t)s0 << 7) + coff);
      const uint2 v1 = *(const uint2*)(h + ((size_t)s1 << 7) + coff);
      const uint2 v2 = *(const uint2*)(h + ((size_t)s2 << 7) + coff);
      const uint2 v3 = *(const uint2*)(h + ((size_t)s3 << 7) + coff);
      ax += (__uint_as_float(v0.x << 16)        + __uint_as_float(v1.x << 16))
          + (__uint_as_float(v2.x << 16)        + __uint_as_float(v3.x << 16));
      ay += (__uint_as_float(v0.x & 0xFFFF0000u) + __uint_as_float(v1.x & 0xFFFF0000u))
          + (__uint_as_float(v2.x & 0xFFFF0000u) + __uint_as_float(v3.x & 0xFFFF0000u));
      az += (__uint_as_float(v0.y << 16)        + __uint_as_float(v1.y << 16))
          + (__uint_as_float(v2.y << 16)        + __uint_as_float(v3.y << 16));
      aw += (__uint_as_float(v0.y & 0xFFFF0000u) + __uint_as_float(v1.y & 0xFFFF0000u))
          + (__uint_as_float(v2.y & 0xFFFF0000u) + __uint_as_float(v3.y & 0xFFFF0000u));
    }
    for (; j < k; j++) {
      const int s0 = __shfl(sidx, j, 32);
      const uint2 v0 = *(const uint2*)(h + ((size_t)s0 << 7) + coff);
      ax += __uint_as_float(v0.x << 16);
      ay += __uint_as_float(v0.x & 0xFFFF0000u);
      az += __uint_as_float(v0.y << 16);
      aw += __uint_as_float(v0.y & 0xFFFF0000u);
    }
  }

  const float s = dis[n];
  const float4 bb = *(const float4*)(b + (lane << 2));
  float4 o;
  o.x = fmaxf(fmaf(s, ax, bb.x), 0.f);
  o.y = fmaxf(fmaf(s, ay, bb.y), 0.f);
  o.z = fmaxf(fmaf(s, az, bb.z), 0.f);
  o.w = fmaxf(fmaf(s, aw, bb.w), 0.f);
  *(float4*)(out + ((size_t)n << 7) + coff) = o;
}

extern "C" void kernel_launch(void* const* d_in, const int* in_sizes, int n_in,
                              void* d_out, int out_size, void* d_ws, size_t ws_size,
                              hipStream_t stream)
{
  const float* x  = (const float*)d_in[0];
  const int* ei   = (const int*)d_in[1];
  const float* W  = (const float*)d_in[2];
  const float* b  = (const float*)d_in[3];
  float* out = (float*)d_out;

  const int Cout = in_sizes[3];            // 128
  const int Cin  = in_sizes[2] / Cout;     // 256
  const int N    = in_sizes[0] / Cin;      // 100000
  const int E    = in_sizes[1] / 2;        // 1600000

  const int* src = ei;
  const int* dst = ei + E;

  char* p = (char*)d_ws;
  size_t off = 0;
  auto alloc = [&](size_t bytes) { char* q = p + off; off = (off + bytes + 255) & ~(size_t)255; return q; };
  unsigned int* cnt     = (unsigned int*)alloc((size_t)N * 4);
  unsigned int* partial = (unsigned int*)alloc(1024 * 4);
  float* dis            = (float*)alloc((size_t)N * 4);
  int* rowptr           = (int*)alloc(((size_t)N + 1) * 4);
  int* cursor           = (int*)alloc((size_t)N * 4);
  int* srcs             = (int*)alloc((size_t)E * 4);
  unsigned short* h     = (unsigned short*)alloc((size_t)N * Cout * 2);  // bf16

  const int nb = (N + 255) / 256;          // 391 <= 1024
  const int gemmB = (N + 31) / 32;         // 3125
  const int scatB = (E + 255) / 256;       // 6250

  k_zero   <<<nb, 256, 0, stream>>>(cnt, N);
  k_count  <<<(E + 255) / 256, 256, 0, stream>>>(dst, cnt, E);
  k_scan1  <<<nb, 256, 0, stream>>>(cnt, partial, N);
  k_scan2  <<<1, 1024, 0, stream>>>(partial, nb);
  k_scan3  <<<nb, 256, 0, stream>>>(cnt, partial, rowptr, cursor, dis, N);
  k_gemm_scatter<<<gemmB + scatB, 256, 0, stream>>>(x, W, dis, h, N,
                                                    src, dst, cursor, srcs, E,
                                                    gemmB, scatB);
  k_aggr   <<<(N + 7) / 8, 256, 0, stream>>>(h, srcs, rowptr, dis, b, out, N);
}